// Round 6
// baseline (4002.550 us; speedup 1.0000x reference)
//
#include <hip/hip_runtime.h>

#define Hdim 128
#define Fdim 16
#define Ddim 16
#define Tdim 8
#define Bdim 2
#define TC 4          // timesteps per chunk (2 chunks)

// chunk row layout: flat row = (n*TC + tin)*Bdim + b  -> per node, the
// TC*Bdim=8 rows (4KB) are CONTIGUOUS, so each pull gather is one 4KB block.

// ---------------- encoder for one chunk -------------------------------------
__global__ __launch_bounds__(256) void enc_kernel(
    const float* __restrict__ xseq, const float* __restrict__ enc_w,
    const float* __restrict__ enc_b, float* __restrict__ x,
    int N, int t0)
{
  int gid = blockIdx.x * 256 + threadIdx.x;
  int row = gid >> 5;          // flat chunk row
  int q   = gid & 31;          // channel quad
  int rowsC = TC * Bdim * N;
  if (row >= rowsC) return;
  int b   = row & 1;
  int nt  = row >> 1;
  int tin = nt & (TC - 1);
  int n   = nt >> 2;           // TC == 4
  const float* xs = xseq + (((size_t)b * Tdim + (t0 + tin)) * N + n) * Fdim;
  float4 acc = ((const float4*)enc_b)[q];
#pragma unroll
  for (int f = 0; f < Fdim; ++f) {
    float s = xs[f];
    float4 w = ((const float4*)enc_w)[f * (Hdim / 4) + q];
    acc.x += s * w.x; acc.y += s * w.y; acc.z += s * w.z; acc.w += s * w.w;
  }
  ((float4*)x)[(size_t)row * (Hdim / 4) + q] = acc;
}

// ---------------- CSR build: count, scan, fill ------------------------------
__global__ __launch_bounds__(256) void count_kernel(
    const int* __restrict__ ei, int* __restrict__ cnt, int E)
{
  int e = blockIdx.x * 256 + threadIdx.x;
  if (e < E) atomicAdd(&cnt[ei[E + e]], 1);
}

__global__ __launch_bounds__(1024) void scan_kernel(
    const int* __restrict__ cnt, int* __restrict__ off, int N)
{
  __shared__ int part[1024];
  int tid = threadIdx.x;
  int per = (N + 1023) / 1024;
  int base = tid * per;
  int s = 0;
  for (int i = 0; i < per; ++i) { int idx = base + i; if (idx < N) s += cnt[idx]; }
  part[tid] = s;
  __syncthreads();
  for (int d = 1; d < 1024; d <<= 1) {
    int v = (tid >= d) ? part[tid - d] : 0;
    __syncthreads();
    part[tid] += v;
    __syncthreads();
  }
  int run = (tid == 0) ? 0 : part[tid - 1];
  for (int i = 0; i < per; ++i) {
    int idx = base + i;
    if (idx < N) { off[idx] = run; run += cnt[idx]; }
  }
  if (tid == 1023) off[N] = part[1023];
}

// fill uses off itself as cursor; afterwards off[d] == start(d+1)
__global__ __launch_bounds__(256) void fill_kernel(
    const int* __restrict__ ei, int* __restrict__ off,
    int* __restrict__ eids, int* __restrict__ src_csr, int E)
{
  int e = blockIdx.x * 256 + threadIdx.x;
  if (e < E) {
    int d = ei[E + e];
    int pos = atomicAdd(&off[d], 1);
    eids[pos] = e;
    src_csr[pos] = ei[e];
  }
}

// ---- pull: one wave per node, all TC timesteps x 2 batches -----------------
// lane c owns channels {2c,2c+1}; per-edge scalars (src, eid, attr) are
// wave-uniform -> scalar pipe. Gather reads one contiguous 4KB block per edge.
__global__ __launch_bounds__(256) void pull_kernel(
    const float* __restrict__ x, float* __restrict__ agg,
    const int* __restrict__ src_csr, const int* __restrict__ off,
    const int* __restrict__ eids, const float* __restrict__ attr,
    const float* __restrict__ eW_l, const float* __restrict__ eb_l,
    int N)
{
  int node = __builtin_amdgcn_readfirstlane(
      blockIdx.x * 4 + (threadIdx.x >> 6));
  if (node >= N) return;
  int c = threadIdx.x & 63;

  float2 w[16];
#pragma unroll
  for (int d = 0; d < 16; ++d) w[d] = ((const float2*)eW_l)[d * 64 + c];
  float2 bq = ((const float2*)eb_l)[c];

  int start = (node == 0) ? 0 : off[node - 1];
  int end   = off[node];

  float2 acc[TC * Bdim];
#pragma unroll
  for (int tb = 0; tb < TC * Bdim; ++tb) { acc[tb].x = 0.f; acc[tb].y = 0.f; }

  const float2* x2 = (const float2*)x;

  for (int i = start; i < end; ++i) {
    int src = src_csr[i];                      // s_load (uniform)
    int e   = eids[i];                         // s_load (uniform)
    const float* av = attr + (size_t)e * 16;
    float2 em = bq;
#pragma unroll
    for (int d = 0; d < 16; ++d) {
      float a = av[d];                         // s_load (uniform)
      em.x += a * w[d].x; em.y += a * w[d].y;
    }
    const float2* xs = x2 + (size_t)src * (TC * Bdim * 64);
#pragma unroll
    for (int tb = 0; tb < TC * Bdim; ++tb) {
      float2 xv = xs[tb * 64 + c];             // contiguous 4KB block
      acc[tb].x += fmaxf(xv.x + em.x, 0.f);
      acc[tb].y += fmaxf(xv.y + em.y, 0.f);
    }
  }

  const float2* xn = x2 + (size_t)node * (TC * Bdim * 64);
  float2* an = (float2*)agg + (size_t)node * (TC * Bdim * 64);
#pragma unroll
  for (int tb = 0; tb < TC * Bdim; ++tb) {
    float2 s = xn[tb * 64 + c];
    float2 o = {acc[tb].x + s.x, acc[tb].y + s.y};
    an[tb * 64 + c] = o;
  }
}

// ------- MLP (H->H relu H->H) + LayerNorm + relu + residual, 32 rows/WG -----
// 256 threads: half h (tid>>7) handles 16 rows; both halves share weight
// cachelines via L1 -> TCC weight traffic halves vs 16-row blocks.
__global__ __launch_bounds__(256) void mlp_ln_kernel(
    float* __restrict__ x, const float* __restrict__ agg,
    const float* __restrict__ m1w, const float* __restrict__ m1b,
    const float* __restrict__ m2w, const float* __restrict__ m2b,
    const float* __restrict__ lng, const float* __restrict__ lnb)
{
  const int ROWS = 16;                    // per half
  int h = threadIdx.x >> 7;
  int j = threadIdx.x & 127;
  int row0 = blockIdx.x * 32 + h * ROWS;
  __shared__ float sMid[32][Hdim];
  __shared__ float red1[4], red2[4];
  float (*sM)[Hdim] = &sMid[h * ROWS];

  float xr[ROWS];
#pragma unroll
  for (int r = 0; r < ROWS; ++r) xr[r] = x[(size_t)(row0 + r) * Hdim + j];

  const float4* agg4 = (const float4*)agg;
  float acc[ROWS];
  float b1 = m1b[j];
#pragma unroll
  for (int r = 0; r < ROWS; ++r) acc[r] = b1;
  for (int i4 = 0; i4 < Hdim / 4; ++i4) {
    float w0 = m1w[(i4 * 4 + 0) * Hdim + j];
    float w1 = m1w[(i4 * 4 + 1) * Hdim + j];
    float w2 = m1w[(i4 * 4 + 2) * Hdim + j];
    float w3 = m1w[(i4 * 4 + 3) * Hdim + j];
#pragma unroll
    for (int r = 0; r < ROWS; ++r) {
      float4 av = agg4[(size_t)(row0 + r) * 32 + i4];   // uniform -> s_load
      acc[r] += av.x * w0 + av.y * w1 + av.z * w2 + av.w * w3;
    }
  }
#pragma unroll
  for (int r = 0; r < ROWS; ++r) sM[r][j] = fmaxf(acc[r], 0.f);
  __syncthreads();

  float b2 = m2b[j];
#pragma unroll
  for (int r = 0; r < ROWS; ++r) acc[r] = b2;
  for (int i4 = 0; i4 < Hdim / 4; ++i4) {
    float w0 = m2w[(i4 * 4 + 0) * Hdim + j];
    float w1 = m2w[(i4 * 4 + 1) * Hdim + j];
    float w2 = m2w[(i4 * 4 + 2) * Hdim + j];
    float w3 = m2w[(i4 * 4 + 3) * Hdim + j];
#pragma unroll
    for (int r = 0; r < ROWS; ++r) {
      float4 mv = *(const float4*)&sM[r][i4 * 4];
      acc[r] += mv.x * w0 + mv.y * w1 + mv.z * w2 + mv.w * w3;
    }
  }

  float gj = lng[j], bj = lnb[j];
  int wid = threadIdx.x >> 6;     // global wave id 0..3
  int lane = threadIdx.x & 63;
#pragma unroll
  for (int r = 0; r < ROWS; ++r) {
    float v = acc[r];
    float s1 = v, s2 = v * v;
#pragma unroll
    for (int off = 32; off >= 1; off >>= 1) {
      s1 += __shfl_xor(s1, off);
      s2 += __shfl_xor(s2, off);
    }
    if (lane == 0) { red1[wid] = s1; red2[wid] = s2; }
    __syncthreads();
    float t1 = red1[2 * h] + red1[2 * h + 1];
    float t2 = red2[2 * h] + red2[2 * h + 1];
    __syncthreads();
    float mu  = t1 * (1.f / Hdim);
    float var = fmaxf(t2 * (1.f / Hdim) - mu * mu, 0.f);
    float y = (v - mu) * rsqrtf(var + 1e-5f) * gj + bj;
    x[(size_t)(row0 + r) * Hdim + j] = fmaxf(y, 0.f) + xr[r];
  }
}

// ---------------- one GRU step, 32 rows/WG (256 threads) --------------------
// state rows are (b*N+n); x rows are (n*TC+tin)*Bdim+b in the chunk buffer.
// RACE NOTE: GEMM phase reads ALL channels of this block's hg rows; write
// phase overwrites them. __syncthreads() orders read-before-write (the r3/r4
// 0.1-absmax bug). Rows are block-private so a workgroup barrier suffices.
__global__ __launch_bounds__(256, 2) void gru_kernel(
    const float* __restrict__ x, float* __restrict__ hg,
    const float* __restrict__ wih, const float* __restrict__ whh,
    const float* __restrict__ bih, const float* __restrict__ bhh,
    int N, int tin)
{
  const int ROWS = 16;                    // per half
  int h = threadIdx.x >> 7;
  int j = threadIdx.x & 127;
  int row0 = blockIdx.x * 32 + h * ROWS;

  int xrow[ROWS];
#pragma unroll
  for (int r = 0; r < ROWS; ++r) {
    int rr = row0 + r;
    int b = rr / N, n = rr - b * N;
    xrow[r] = (n * TC + tin) * Bdim + b;
  }

  float air[ROWS], aiz[ROWS], ain[ROWS], ahr[ROWS], ahz[ROWS], ahn[ROWS];
  float bir = bih[j], biz = bih[Hdim + j], bin_ = bih[2 * Hdim + j];
  float bhr = bhh[j], bhz = bhh[Hdim + j], bhn = bhh[2 * Hdim + j];
#pragma unroll
  for (int r = 0; r < ROWS; ++r) {
    air[r] = bir; aiz[r] = biz; ain[r] = bin_;
    ahr[r] = bhr; ahz[r] = bhz; ahn[r] = bhn;
  }

  const float2* x2 = (const float2*)x;
  const float2* h2 = (const float2*)hg;
  for (int i2 = 0; i2 < Hdim / 2; ++i2) {
    int i = i2 * 2;
    float w0a = wih[(i + 0) * 384 + j], w0b = wih[(i + 0) * 384 + 128 + j], w0c = wih[(i + 0) * 384 + 256 + j];
    float w1a = wih[(i + 1) * 384 + j], w1b = wih[(i + 1) * 384 + 128 + j], w1c = wih[(i + 1) * 384 + 256 + j];
    float v0a = whh[(i + 0) * 384 + j], v0b = whh[(i + 0) * 384 + 128 + j], v0c = whh[(i + 0) * 384 + 256 + j];
    float v1a = whh[(i + 1) * 384 + j], v1b = whh[(i + 1) * 384 + 128 + j], v1c = whh[(i + 1) * 384 + 256 + j];
#pragma unroll
    for (int r = 0; r < ROWS; ++r) {
      float2 xv = x2[(size_t)xrow[r] * 64 + i2];
      float2 hv = h2[(size_t)(row0 + r) * 64 + i2];
      air[r] += xv.x * w0a + xv.y * w1a;
      aiz[r] += xv.x * w0b + xv.y * w1b;
      ain[r] += xv.x * w0c + xv.y * w1c;
      ahr[r] += hv.x * v0a + hv.y * v1a;
      ahz[r] += hv.x * v0b + hv.y * v1b;
      ahn[r] += hv.x * v0c + hv.y * v1c;
    }
  }

  __syncthreads();   // all waves finish reading hg before any wave writes it

#pragma unroll
  for (int r = 0; r < ROWS; ++r) {
    float rr = 1.f / (1.f + expf(-(air[r] + ahr[r])));
    float zz = 1.f / (1.f + expf(-(aiz[r] + ahz[r])));
    float nn = tanhf(ain[r] + rr * ahn[r]);
    float hold = hg[(size_t)(row0 + r) * Hdim + j];
    hg[(size_t)(row0 + r) * Hdim + j] = (1.f - zz) * nn + zz * hold;
  }
}

// ---------------- head: out[row] = dot(h[row], head_w) + head_b -------------
__global__ __launch_bounds__(128) void head_kernel(
    const float* __restrict__ hg, const float* __restrict__ hw,
    const float* __restrict__ hb, float* __restrict__ out)
{
  int row = blockIdx.x;
  int j = threadIdx.x;
  __shared__ float red[2];
  float v = hg[(size_t)row * Hdim + j] * hw[j];
#pragma unroll
  for (int off = 32; off >= 1; off >>= 1) v += __shfl_xor(v, off);
  int wid = j >> 6, lane = j & 63;
  if (lane == 0) red[wid] = v;
  __syncthreads();
  if (j == 0) out[row] = red[0] + red[1] + hb[0];
}

extern "C" void kernel_launch(void* const* d_in, const int* in_sizes, int n_in,
                              void* d_out, int out_size, void* d_ws, size_t ws_size,
                              hipStream_t stream)
{
  const float* xseq  = (const float*)d_in[0];
  const int*   ei    = (const int*)d_in[1];
  const float* attr  = (const float*)d_in[2];
  const float* enc_w = (const float*)d_in[3];
  const float* enc_b = (const float*)d_in[4];
  const float* eW    = (const float*)d_in[5];
  const float* eb    = (const float*)d_in[6];
  const float* m1w   = (const float*)d_in[7];
  const float* m1b   = (const float*)d_in[8];
  const float* m2w   = (const float*)d_in[9];
  const float* m2b   = (const float*)d_in[10];
  const float* lng   = (const float*)d_in[11];
  const float* lnb   = (const float*)d_in[12];
  const float* wih   = (const float*)d_in[13];
  const float* whh   = (const float*)d_in[14];
  const float* bih   = (const float*)d_in[15];
  const float* bhh   = (const float*)d_in[16];
  const float* hw    = (const float*)d_in[17];
  const float* hb    = (const float*)d_in[18];

  int E = in_sizes[1] / 2;
  int N = in_sizes[0] / (Bdim * Tdim * Fdim);
  int rowsState = Bdim * N;                    // 20000
  int rowsC = TC * Bdim * N;                   // 80000
  size_t SC = (size_t)rowsC * Hdim;            // chunk buffer floats
  size_t SS = (size_t)rowsState * Hdim;        // state buffer floats

  float* x    = (float*)d_ws;
  float* agg  = x + SC;
  float* hgb  = agg + SC;
  int*   cnt  = (int*)(hgb + SS);
  int*   off  = cnt + N;
  int*   eids = off + (N + 1);
  int*   src_csr = eids + E;

  hipMemsetAsync(hgb, 0, SS * sizeof(float), stream);
  hipMemsetAsync(cnt, 0, N * sizeof(int), stream);

  int eBlocks    = (E + 255) / 256;
  int encBlocks  = (rowsC * 32 + 255) / 256;   // 10000
  int mlpBlocks  = rowsC / 32;                 // 2500
  int gruBlocks  = rowsState / 32;             // 625
  int pullBlocks = (N + 3) / 4;                // 2500

  count_kernel<<<eBlocks, 256, 0, stream>>>(ei, cnt, E);
  scan_kernel<<<1, 1024, 0, stream>>>(cnt, off, N);
  fill_kernel<<<eBlocks, 256, 0, stream>>>(ei, off, eids, src_csr, E);

  for (int c = 0; c < Tdim / TC; ++c) {
    enc_kernel<<<encBlocks, 256, 0, stream>>>(xseq, enc_w, enc_b, x, N, c * TC);
    for (int l = 0; l < 2; ++l) {
      pull_kernel<<<pullBlocks, 256, 0, stream>>>(
          x, agg, src_csr, off, eids, attr,
          eW + (size_t)l * Ddim * Hdim, eb + (size_t)l * Hdim, N);
      mlp_ln_kernel<<<mlpBlocks, 256, 0, stream>>>(
          x, agg, m1w + (size_t)l * Hdim * Hdim, m1b + (size_t)l * Hdim,
          m2w + (size_t)l * Hdim * Hdim, m2b + (size_t)l * Hdim,
          lng + (size_t)l * Hdim, lnb + (size_t)l * Hdim);
    }
    for (int tin = 0; tin < TC; ++tin)
      gru_kernel<<<gruBlocks, 256, 0, stream>>>(x, hgb, wih, whh, bih, bhh, N, tin);
  }
  head_kernel<<<rowsState, 128, 0, stream>>>(hgb, hw, hb, (float*)d_out);
}

// Round 7
// 2117.509 us; speedup vs baseline: 1.8902x; 1.8902x over previous
//
#include <hip/hip_runtime.h>

#define Hdim 128
#define Fdim 16
#define Ddim 16
#define Tdim 8
#define Bdim 2
#define TC 4          // timesteps per chunk (2 chunks)

typedef _Float16 h2 __attribute__((ext_vector_type(2)));
typedef _Float16 h4 __attribute__((ext_vector_type(4)));

// chunk row layout: flat row = (n*TC + tin)*Bdim + b  -> per node, the
// TC*Bdim=8 rows (4KB fp32 / 2KB fp16) are CONTIGUOUS: one block per gather.
// xh is an fp16 shadow of x used ONLY for neighbor gathers (self/emb/acc fp32).

// ---------------- encoder for one chunk: writes x (fp32) + xh (fp16) --------
__global__ __launch_bounds__(256) void enc_kernel(
    const float* __restrict__ xseq, const float* __restrict__ enc_w,
    const float* __restrict__ enc_b, float* __restrict__ x,
    _Float16* __restrict__ xh, int N, int t0)
{
  int gid = blockIdx.x * 256 + threadIdx.x;
  int row = gid >> 5;          // flat chunk row
  int q   = gid & 31;          // channel quad
  int rowsC = TC * Bdim * N;
  if (row >= rowsC) return;
  int b   = row & 1;
  int nt  = row >> 1;
  int tin = nt & (TC - 1);
  int n   = nt >> 2;           // TC == 4
  const float* xs = xseq + (((size_t)b * Tdim + (t0 + tin)) * N + n) * Fdim;
  float4 acc = ((const float4*)enc_b)[q];
#pragma unroll
  for (int f = 0; f < Fdim; ++f) {
    float s = xs[f];
    float4 w = ((const float4*)enc_w)[f * (Hdim / 4) + q];
    acc.x += s * w.x; acc.y += s * w.y; acc.z += s * w.z; acc.w += s * w.w;
  }
  ((float4*)x)[(size_t)row * (Hdim / 4) + q] = acc;
  h4 hv = { (_Float16)acc.x, (_Float16)acc.y, (_Float16)acc.z, (_Float16)acc.w };
  *(h4*)(xh + (size_t)row * Hdim + q * 4) = hv;
}

// ---------------- CSR build: count, scan, fill ------------------------------
__global__ __launch_bounds__(256) void count_kernel(
    const int* __restrict__ ei, int* __restrict__ cnt, int E)
{
  int e = blockIdx.x * 256 + threadIdx.x;
  if (e < E) atomicAdd(&cnt[ei[E + e]], 1);
}

__global__ __launch_bounds__(1024) void scan_kernel(
    const int* __restrict__ cnt, int* __restrict__ off, int N)
{
  __shared__ int part[1024];
  int tid = threadIdx.x;
  int per = (N + 1023) / 1024;
  int base = tid * per;
  int s = 0;
  for (int i = 0; i < per; ++i) { int idx = base + i; if (idx < N) s += cnt[idx]; }
  part[tid] = s;
  __syncthreads();
  for (int d = 1; d < 1024; d <<= 1) {
    int v = (tid >= d) ? part[tid - d] : 0;
    __syncthreads();
    part[tid] += v;
    __syncthreads();
  }
  int run = (tid == 0) ? 0 : part[tid - 1];
  for (int i = 0; i < per; ++i) {
    int idx = base + i;
    if (idx < N) { off[idx] = run; run += cnt[idx]; }
  }
  if (tid == 1023) off[N] = part[1023];
}

// fill uses off itself as cursor; afterwards off[d] == start(d+1)
__global__ __launch_bounds__(256) void fill_kernel(
    const int* __restrict__ ei, int* __restrict__ off,
    int* __restrict__ eids, int* __restrict__ src_csr, int E)
{
  int e = blockIdx.x * 256 + threadIdx.x;
  if (e < E) {
    int d = ei[E + e];
    int pos = atomicAdd(&off[d], 1);
    eids[pos] = e;
    src_csr[pos] = ei[e];
  }
}

// ---- pull: one wave per node, all TC timesteps x 2 batches -----------------
// lane c owns channels {2c,2c+1}; per-edge scalars (src, eid, attr) are
// wave-uniform -> scalar pipe. Neighbor gather reads the fp16 shadow (2KB
// contiguous per edge, halves L2-miss traffic); emb/self/acc stay fp32.
__global__ __launch_bounds__(256) void pull_kernel(
    const float* __restrict__ x, const _Float16* __restrict__ xh,
    float* __restrict__ agg,
    const int* __restrict__ src_csr, const int* __restrict__ off,
    const int* __restrict__ eids, const float* __restrict__ attr,
    const float* __restrict__ eW_l, const float* __restrict__ eb_l,
    int N)
{
  int node = __builtin_amdgcn_readfirstlane(
      blockIdx.x * 4 + (threadIdx.x >> 6));
  if (node >= N) return;
  int c = threadIdx.x & 63;

  float2 w[16];
#pragma unroll
  for (int d = 0; d < 16; ++d) w[d] = ((const float2*)eW_l)[d * 64 + c];
  float2 bq = ((const float2*)eb_l)[c];

  int start = (node == 0) ? 0 : off[node - 1];
  int end   = off[node];

  float2 acc[TC * Bdim];
#pragma unroll
  for (int tb = 0; tb < TC * Bdim; ++tb) { acc[tb].x = 0.f; acc[tb].y = 0.f; }

  for (int i = start; i < end; ++i) {
    int src = src_csr[i];                      // s_load (uniform)
    int e   = eids[i];                         // s_load (uniform)
    const float* av = attr + (size_t)e * 16;
    float2 em = bq;
#pragma unroll
    for (int d = 0; d < 16; ++d) {
      float a = av[d];                         // s_load (uniform)
      em.x += a * w[d].x; em.y += a * w[d].y;
    }
    const h2* xs = (const h2*)(xh + (size_t)src * (TC * Bdim * Hdim)) + c;
#pragma unroll
    for (int tb = 0; tb < TC * Bdim; ++tb) {
      h2 xv = xs[tb * 64];                     // contiguous 2KB block
      acc[tb].x += fmaxf((float)xv.x + em.x, 0.f);
      acc[tb].y += fmaxf((float)xv.y + em.y, 0.f);
    }
  }

  const float2* xn = (const float2*)x + (size_t)node * (TC * Bdim * 64);
  float2* an = (float2*)agg + (size_t)node * (TC * Bdim * 64);
#pragma unroll
  for (int tb = 0; tb < TC * Bdim; ++tb) {
    float2 s = xn[tb * 64 + c];                // self term, exact fp32
    float2 o = {acc[tb].x + s.x, acc[tb].y + s.y};
    an[tb * 64 + c] = o;
  }
}

// ------- MLP (H->H relu H->H) + LayerNorm + relu + residual, 16 rows/WG -----
// 128 threads, row0 from blockIdx ONLY: keeps agg/x row reads wave-uniform
// (s_load). r6 regression lesson: deriving row0 from threadIdx makes LLVM
// mark every row read divergent -> vector loads -> latency-bound.
// Also refreshes the fp16 shadow xh for the next layer's pull.
__global__ __launch_bounds__(128) void mlp_ln_kernel(
    float* __restrict__ x, _Float16* __restrict__ xh,
    const float* __restrict__ agg,
    const float* __restrict__ m1w, const float* __restrict__ m1b,
    const float* __restrict__ m2w, const float* __restrict__ m2b,
    const float* __restrict__ lng, const float* __restrict__ lnb)
{
  const int ROWS = 16;
  int row0 = blockIdx.x * ROWS;
  int j = threadIdx.x;
  __shared__ float sMid[ROWS][Hdim];
  __shared__ float red1[2], red2[2];

  float xr[ROWS];
#pragma unroll
  for (int r = 0; r < ROWS; ++r) xr[r] = x[(size_t)(row0 + r) * Hdim + j];

  const float4* agg4 = (const float4*)agg;
  float acc[ROWS];
  float b1 = m1b[j];
#pragma unroll
  for (int r = 0; r < ROWS; ++r) acc[r] = b1;
  for (int i4 = 0; i4 < Hdim / 4; ++i4) {
    float w0 = m1w[(i4 * 4 + 0) * Hdim + j];
    float w1 = m1w[(i4 * 4 + 1) * Hdim + j];
    float w2 = m1w[(i4 * 4 + 2) * Hdim + j];
    float w3 = m1w[(i4 * 4 + 3) * Hdim + j];
#pragma unroll
    for (int r = 0; r < ROWS; ++r) {
      float4 av = agg4[(size_t)(row0 + r) * 32 + i4];   // uniform -> s_load
      acc[r] += av.x * w0 + av.y * w1 + av.z * w2 + av.w * w3;
    }
  }
#pragma unroll
  for (int r = 0; r < ROWS; ++r) sMid[r][j] = fmaxf(acc[r], 0.f);
  __syncthreads();

  float b2 = m2b[j];
#pragma unroll
  for (int r = 0; r < ROWS; ++r) acc[r] = b2;
  for (int i4 = 0; i4 < Hdim / 4; ++i4) {
    float w0 = m2w[(i4 * 4 + 0) * Hdim + j];
    float w1 = m2w[(i4 * 4 + 1) * Hdim + j];
    float w2 = m2w[(i4 * 4 + 2) * Hdim + j];
    float w3 = m2w[(i4 * 4 + 3) * Hdim + j];
#pragma unroll
    for (int r = 0; r < ROWS; ++r) {
      float4 mv = *(const float4*)&sMid[r][i4 * 4];
      acc[r] += mv.x * w0 + mv.y * w1 + mv.z * w2 + mv.w * w3;
    }
  }

  float gj = lng[j], bj = lnb[j];
  int wid = j >> 6, lane = j & 63;
#pragma unroll
  for (int r = 0; r < ROWS; ++r) {
    float v = acc[r];
    float s1 = v, s2 = v * v;
#pragma unroll
    for (int off = 32; off >= 1; off >>= 1) {
      s1 += __shfl_xor(s1, off);
      s2 += __shfl_xor(s2, off);
    }
    if (lane == 0) { red1[wid] = s1; red2[wid] = s2; }
    __syncthreads();
    float t1 = red1[0] + red1[1];
    float t2 = red2[0] + red2[1];
    __syncthreads();
    float mu  = t1 * (1.f / Hdim);
    float var = fmaxf(t2 * (1.f / Hdim) - mu * mu, 0.f);
    float y = (v - mu) * rsqrtf(var + 1e-5f) * gj + bj;
    float o = fmaxf(y, 0.f) + xr[r];
    x[(size_t)(row0 + r) * Hdim + j] = o;
    xh[(size_t)(row0 + r) * Hdim + j] = (_Float16)o;
  }
}

// ---------------- one GRU step, 16 rows/WG (128 threads) --------------------
// state rows are (b*N+n); x rows are (n*TC+tin)*Bdim+b in the chunk buffer.
// RACE NOTE: GEMM phase reads ALL channels of this block's hg rows; write
// phase overwrites them. __syncthreads() orders read-before-write (the r3/r4
// 0.1-absmax bug). Rows are block-private so a workgroup barrier suffices.
__global__ __launch_bounds__(128, 2) void gru_kernel(
    const float* __restrict__ x, float* __restrict__ hg,
    const float* __restrict__ wih, const float* __restrict__ whh,
    const float* __restrict__ bih, const float* __restrict__ bhh,
    int N, int tin)
{
  const int ROWS = 16;
  int row0 = blockIdx.x * ROWS;
  int j = threadIdx.x;

  int xrow[ROWS];
#pragma unroll
  for (int r = 0; r < ROWS; ++r) {
    int rr = row0 + r;
    int b = rr / N, n = rr - b * N;
    xrow[r] = (n * TC + tin) * Bdim + b;
  }

  float air[ROWS], aiz[ROWS], ain[ROWS], ahr[ROWS], ahz[ROWS], ahn[ROWS];
  float bir = bih[j], biz = bih[Hdim + j], bin_ = bih[2 * Hdim + j];
  float bhr = bhh[j], bhz = bhh[Hdim + j], bhn = bhh[2 * Hdim + j];
#pragma unroll
  for (int r = 0; r < ROWS; ++r) {
    air[r] = bir; aiz[r] = biz; ain[r] = bin_;
    ahr[r] = bhr; ahz[r] = bhz; ahn[r] = bhn;
  }

  const float2* x2 = (const float2*)x;
  const float2* h2p = (const float2*)hg;
  for (int i2 = 0; i2 < Hdim / 2; ++i2) {
    int i = i2 * 2;
    float w0a = wih[(i + 0) * 384 + j], w0b = wih[(i + 0) * 384 + 128 + j], w0c = wih[(i + 0) * 384 + 256 + j];
    float w1a = wih[(i + 1) * 384 + j], w1b = wih[(i + 1) * 384 + 128 + j], w1c = wih[(i + 1) * 384 + 256 + j];
    float v0a = whh[(i + 0) * 384 + j], v0b = whh[(i + 0) * 384 + 128 + j], v0c = whh[(i + 0) * 384 + 256 + j];
    float v1a = whh[(i + 1) * 384 + j], v1b = whh[(i + 1) * 384 + 128 + j], v1c = whh[(i + 1) * 384 + 256 + j];
#pragma unroll
    for (int r = 0; r < ROWS; ++r) {
      float2 xv = x2[(size_t)xrow[r] * 64 + i2];         // uniform -> s_load
      float2 hv = h2p[(size_t)(row0 + r) * 64 + i2];     // uniform -> s_load
      air[r] += xv.x * w0a + xv.y * w1a;
      aiz[r] += xv.x * w0b + xv.y * w1b;
      ain[r] += xv.x * w0c + xv.y * w1c;
      ahr[r] += hv.x * v0a + hv.y * v1a;
      ahz[r] += hv.x * v0b + hv.y * v1b;
      ahn[r] += hv.x * v0c + hv.y * v1c;
    }
  }

  __syncthreads();   // all waves finish reading hg before any wave writes it

#pragma unroll
  for (int r = 0; r < ROWS; ++r) {
    float rr = 1.f / (1.f + expf(-(air[r] + ahr[r])));
    float zz = 1.f / (1.f + expf(-(aiz[r] + ahz[r])));
    float nn = tanhf(ain[r] + rr * ahn[r]);
    float hold = hg[(size_t)(row0 + r) * Hdim + j];
    hg[(size_t)(row0 + r) * Hdim + j] = (1.f - zz) * nn + zz * hold;
  }
}

// ---------------- head: out[row] = dot(h[row], head_w) + head_b -------------
__global__ __launch_bounds__(128) void head_kernel(
    const float* __restrict__ hg, const float* __restrict__ hw,
    const float* __restrict__ hb, float* __restrict__ out)
{
  int row = blockIdx.x;
  int j = threadIdx.x;
  __shared__ float red[2];
  float v = hg[(size_t)row * Hdim + j] * hw[j];
#pragma unroll
  for (int off = 32; off >= 1; off >>= 1) v += __shfl_xor(v, off);
  int wid = j >> 6, lane = j & 63;
  if (lane == 0) red[wid] = v;
  __syncthreads();
  if (j == 0) out[row] = red[0] + red[1] + hb[0];
}

extern "C" void kernel_launch(void* const* d_in, const int* in_sizes, int n_in,
                              void* d_out, int out_size, void* d_ws, size_t ws_size,
                              hipStream_t stream)
{
  const float* xseq  = (const float*)d_in[0];
  const int*   ei    = (const int*)d_in[1];
  const float* attr  = (const float*)d_in[2];
  const float* enc_w = (const float*)d_in[3];
  const float* enc_b = (const float*)d_in[4];
  const float* eW    = (const float*)d_in[5];
  const float* eb    = (const float*)d_in[6];
  const float* m1w   = (const float*)d_in[7];
  const float* m1b   = (const float*)d_in[8];
  const float* m2w   = (const float*)d_in[9];
  const float* m2b   = (const float*)d_in[10];
  const float* lng   = (const float*)d_in[11];
  const float* lnb   = (const float*)d_in[12];
  const float* wih   = (const float*)d_in[13];
  const float* whh   = (const float*)d_in[14];
  const float* bih   = (const float*)d_in[15];
  const float* bhh   = (const float*)d_in[16];
  const float* hw    = (const float*)d_in[17];
  const float* hb    = (const float*)d_in[18];

  int E = in_sizes[1] / 2;
  int N = in_sizes[0] / (Bdim * Tdim * Fdim);
  int rowsState = Bdim * N;                    // 20000
  int rowsC = TC * Bdim * N;                   // 80000
  size_t SC = (size_t)rowsC * Hdim;            // chunk buffer floats
  size_t SS = (size_t)rowsState * Hdim;        // state buffer floats

  float*     x   = (float*)d_ws;
  float*     agg = x + SC;
  float*     hgb = agg + SC;
  _Float16*  xh  = (_Float16*)(hgb + SS);      // fp16 shadow, SC elements
  int*   cnt  = (int*)(xh + SC);
  int*   off  = cnt + N;
  int*   eids = off + (N + 1);
  int*   src_csr = eids + E;

  hipMemsetAsync(hgb, 0, SS * sizeof(float), stream);
  hipMemsetAsync(cnt, 0, N * sizeof(int), stream);

  int eBlocks    = (E + 255) / 256;
  int encBlocks  = (rowsC * 32 + 255) / 256;   // 10000
  int mlpBlocks  = rowsC / 16;                 // 5000
  int gruBlocks  = rowsState / 16;             // 1250
  int pullBlocks = (N + 3) / 4;                // 2500

  count_kernel<<<eBlocks, 256, 0, stream>>>(ei, cnt, E);
  scan_kernel<<<1, 1024, 0, stream>>>(cnt, off, N);
  fill_kernel<<<eBlocks, 256, 0, stream>>>(ei, off, eids, src_csr, E);

  for (int c = 0; c < Tdim / TC; ++c) {
    enc_kernel<<<encBlocks, 256, 0, stream>>>(xseq, enc_w, enc_b, x, xh, N, c * TC);
    for (int l = 0; l < 2; ++l) {
      pull_kernel<<<pullBlocks, 256, 0, stream>>>(
          x, xh, agg, src_csr, off, eids, attr,
          eW + (size_t)l * Ddim * Hdim, eb + (size_t)l * Hdim, N);
      mlp_ln_kernel<<<mlpBlocks, 128, 0, stream>>>(
          x, xh, agg, m1w + (size_t)l * Hdim * Hdim, m1b + (size_t)l * Hdim,
          m2w + (size_t)l * Hdim * Hdim, m2b + (size_t)l * Hdim,
          lng + (size_t)l * Hdim, lnb + (size_t)l * Hdim);
    }
    for (int tin = 0; tin < TC; ++tin)
      gru_kernel<<<gruBlocks, 128, 0, stream>>>(x, hgb, wih, whh, bih, bhh, N, tin);
  }
  head_kernel<<<rowsState, 128, 0, stream>>>(hgb, hw, hb, (float*)d_out);
}

// Round 8
// 1785.777 us; speedup vs baseline: 2.2413x; 1.1858x over previous
//
#include <hip/hip_runtime.h>

#define Hdim 128
#define Fdim 16
#define Ddim 16
#define Tdim 8
#define Bdim 2
#define TC 4          // timesteps per chunk (2 chunks)

typedef _Float16 h2 __attribute__((ext_vector_type(2)));
typedef _Float16 h4 __attribute__((ext_vector_type(4)));
typedef _Float16 half8 __attribute__((ext_vector_type(8)));
typedef float floatx4 __attribute__((ext_vector_type(4)));

// chunk row layout: flat row = (n*TC + tin)*Bdim + b  -> per node, the
// TC*Bdim=8 rows (4KB fp32 / 2KB fp16) are CONTIGUOUS: one block per gather.
// xh is an fp16 shadow of x used ONLY for neighbor gathers (self/emb/acc fp32).

// ---------------- encoder for one chunk: writes x (fp32) + xh (fp16) --------
__global__ __launch_bounds__(256) void enc_kernel(
    const float* __restrict__ xseq, const float* __restrict__ enc_w,
    const float* __restrict__ enc_b, float* __restrict__ x,
    _Float16* __restrict__ xh, int N, int t0)
{
  int gid = blockIdx.x * 256 + threadIdx.x;
  int row = gid >> 5;          // flat chunk row
  int q   = gid & 31;          // channel quad
  int rowsC = TC * Bdim * N;
  if (row >= rowsC) return;
  int b   = row & 1;
  int nt  = row >> 1;
  int tin = nt & (TC - 1);
  int n   = nt >> 2;           // TC == 4
  const float* xs = xseq + (((size_t)b * Tdim + (t0 + tin)) * N + n) * Fdim;
  float4 acc = ((const float4*)enc_b)[q];
#pragma unroll
  for (int f = 0; f < Fdim; ++f) {
    float s = xs[f];
    float4 w = ((const float4*)enc_w)[f * (Hdim / 4) + q];
    acc.x += s * w.x; acc.y += s * w.y; acc.z += s * w.z; acc.w += s * w.w;
  }
  ((float4*)x)[(size_t)row * (Hdim / 4) + q] = acc;
  h4 hv = { (_Float16)acc.x, (_Float16)acc.y, (_Float16)acc.z, (_Float16)acc.w };
  *(h4*)(xh + (size_t)row * Hdim + q * 4) = hv;
}

// ---------------- CSR build: count, scan, fill ------------------------------
__global__ __launch_bounds__(256) void count_kernel(
    const int* __restrict__ ei, int* __restrict__ cnt, int E)
{
  int e = blockIdx.x * 256 + threadIdx.x;
  if (e < E) atomicAdd(&cnt[ei[E + e]], 1);
}

__global__ __launch_bounds__(1024) void scan_kernel(
    const int* __restrict__ cnt, int* __restrict__ off, int N)
{
  __shared__ int part[1024];
  int tid = threadIdx.x;
  int per = (N + 1023) / 1024;
  int base = tid * per;
  int s = 0;
  for (int i = 0; i < per; ++i) { int idx = base + i; if (idx < N) s += cnt[idx]; }
  part[tid] = s;
  __syncthreads();
  for (int d = 1; d < 1024; d <<= 1) {
    int v = (tid >= d) ? part[tid - d] : 0;
    __syncthreads();
    part[tid] += v;
    __syncthreads();
  }
  int run = (tid == 0) ? 0 : part[tid - 1];
  for (int i = 0; i < per; ++i) {
    int idx = base + i;
    if (idx < N) { off[idx] = run; run += cnt[idx]; }
  }
  if (tid == 1023) off[N] = part[1023];
}

// fill uses off itself as cursor; afterwards off[d] == start(d+1)
__global__ __launch_bounds__(256) void fill_kernel(
    const int* __restrict__ ei, int* __restrict__ off,
    int* __restrict__ eids, int* __restrict__ src_csr, int E)
{
  int e = blockIdx.x * 256 + threadIdx.x;
  if (e < E) {
    int d = ei[E + e];
    int pos = atomicAdd(&off[d], 1);
    eids[pos] = e;
    src_csr[pos] = ei[e];
  }
}

// ---- pack a [128][128] fp32 weight matrix into MFMA B-fragment order -------
// frag (nt, ks, lane): element W[ks*32 + (lane>>4)*8 + j][nt*16 + (lane&15)]
__global__ __launch_bounds__(256) void pack_w_kernel(
    const float* __restrict__ W, _Float16* __restrict__ Wp)
{
  int t = blockIdx.x * 256 + threadIdx.x;   // 2048 frag-lanes
  if (t >= 2048) return;
  int lane = t & 63, ks = (t >> 6) & 3, nt = t >> 8;
  int col = nt * 16 + (lane & 15);
  int k0  = ks * 32 + (lane >> 4) * 8;
  half8 o;
#pragma unroll
  for (int j = 0; j < 8; ++j) o[j] = (_Float16)W[(k0 + j) * Hdim + col];
  *(half8*)(Wp + (size_t)t * 8) = o;
}

// ---- pull: one wave per node, all TC timesteps x 2 batches -----------------
// lane c owns channels {2c,2c+1}; per-edge scalars (src, eid, attr) are
// wave-uniform -> scalar pipe. Neighbor gather reads the fp16 shadow (2KB
// contiguous per edge, halves L2-miss traffic); emb/self/acc stay fp32.
__global__ __launch_bounds__(256) void pull_kernel(
    const float* __restrict__ x, const _Float16* __restrict__ xh,
    float* __restrict__ agg,
    const int* __restrict__ src_csr, const int* __restrict__ off,
    const int* __restrict__ eids, const float* __restrict__ attr,
    const float* __restrict__ eW_l, const float* __restrict__ eb_l,
    int N)
{
  int node = __builtin_amdgcn_readfirstlane(
      blockIdx.x * 4 + (threadIdx.x >> 6));
  if (node >= N) return;
  int c = threadIdx.x & 63;

  float2 w[16];
#pragma unroll
  for (int d = 0; d < 16; ++d) w[d] = ((const float2*)eW_l)[d * 64 + c];
  float2 bq = ((const float2*)eb_l)[c];

  int start = (node == 0) ? 0 : off[node - 1];
  int end   = off[node];

  float2 acc[TC * Bdim];
#pragma unroll
  for (int tb = 0; tb < TC * Bdim; ++tb) { acc[tb].x = 0.f; acc[tb].y = 0.f; }

  for (int i = start; i < end; ++i) {
    int src = src_csr[i];                      // s_load (uniform)
    int e   = eids[i];                         // s_load (uniform)
    const float* av = attr + (size_t)e * 16;
    float2 em = bq;
#pragma unroll
    for (int d = 0; d < 16; ++d) {
      float a = av[d];                         // s_load (uniform)
      em.x += a * w[d].x; em.y += a * w[d].y;
    }
    const h2* xs = (const h2*)(xh + (size_t)src * (TC * Bdim * Hdim)) + c;
#pragma unroll
    for (int tb = 0; tb < TC * Bdim; ++tb) {
      h2 xv = xs[tb * 64];                     // contiguous 2KB block
      acc[tb].x += fmaxf((float)xv.x + em.x, 0.f);
      acc[tb].y += fmaxf((float)xv.y + em.y, 0.f);
    }
  }

  const float2* xn = (const float2*)x + (size_t)node * (TC * Bdim * 64);
  float2* an = (float2*)agg + (size_t)node * (TC * Bdim * 64);
#pragma unroll
  for (int tb = 0; tb < TC * Bdim; ++tb) {
    float2 s = xn[tb * 64 + c];                // self term, exact fp32
    float2 o = {acc[tb].x + s.x, acc[tb].y + s.y};
    an[tb * 64 + c] = o;
  }
}

// ------- MLP via MFMA: relu(agg@W1+b1)@W2+b2 -> LN -> relu -> +x ------------
// 4 waves/block, 16 rows/wave, N=128 in 8 tiles of 16, K=128 in 4 steps of 32.
// MFMA mappings (AMD matrix-core layout, C/D verified in guide m89):
//   A: row=lane&15, k=(lane>>4)*8+j   B: col=lane&15, k=(lane>>4)*8+j
//   D: col=lane&15, row=(lane>>4)*4+reg
// mid staged in wave-private LDS [16][132] (pad -> 2-way banks, free).
// Epilogue (bias, LN stats via quarter-wave shfl_xor, relu, residual) fp32.
__global__ __launch_bounds__(256) void mlp_mfma_kernel(
    float* __restrict__ x, _Float16* __restrict__ xh,
    const float* __restrict__ agg,
    const _Float16* __restrict__ w1p, const _Float16* __restrict__ w2p,
    const float* __restrict__ m1b, const float* __restrict__ m2b,
    const float* __restrict__ lng, const float* __restrict__ lnb)
{
  __shared__ float mid[4][16][132];
  int wid  = threadIdx.x >> 6;
  int lane = threadIdx.x & 63;
  int row0 = blockIdx.x * 64 + wid * 16;
  int mrow = lane & 15;          // A-row / D-col index
  int kgrp = lane >> 4;          // 0..3

  // A frags from agg (fp32 -> fp16 RNE)
  half8 afrag[4];
  const float* abase = agg + (size_t)(row0 + mrow) * Hdim + kgrp * 8;
#pragma unroll
  for (int ks = 0; ks < 4; ++ks) {
    const float* p = abase + ks * 32;
    half8 a;
#pragma unroll
    for (int j = 0; j < 8; ++j) a[j] = (_Float16)p[j];
    afrag[ks] = a;
  }

  float (*midw)[132] = mid[wid];
  // ---- GEMM1 + bias + relu -> mid ----
#pragma unroll
  for (int nt = 0; nt < 8; ++nt) {
    floatx4 acc = {0.f, 0.f, 0.f, 0.f};
#pragma unroll
    for (int ks = 0; ks < 4; ++ks) {
      half8 b = *(const half8*)(w1p + ((size_t)(nt * 4 + ks) * 64 + lane) * 8);
      acc = __builtin_amdgcn_mfma_f32_16x16x32_f16(afrag[ks], b, acc, 0, 0, 0);
    }
    int col = nt * 16 + mrow;
    float bv = m1b[col];
#pragma unroll
    for (int r = 0; r < 4; ++r)
      midw[kgrp * 4 + r][col] = fmaxf(acc[r] + bv, 0.f);
  }
  // wave-private LDS: same wave reads below; compiler inserts lgkmcnt waits.

  // A frags for GEMM2 from mid
  half8 afrag2[4];
#pragma unroll
  for (int ks = 0; ks < 4; ++ks) {
    const float* p = &midw[mrow][kgrp * 8 + ks * 32];
    half8 a;
#pragma unroll
    for (int j = 0; j < 8; ++j) a[j] = (_Float16)p[j];
    afrag2[ks] = a;
  }

  // ---- GEMM2 + bias ----
  floatx4 acc2[8];
#pragma unroll
  for (int nt = 0; nt < 8; ++nt) {
    floatx4 acc = {0.f, 0.f, 0.f, 0.f};
#pragma unroll
    for (int ks = 0; ks < 4; ++ks) {
      half8 b = *(const half8*)(w2p + ((size_t)(nt * 4 + ks) * 64 + lane) * 8);
      acc = __builtin_amdgcn_mfma_f32_16x16x32_f16(afrag2[ks], b, acc, 0, 0, 0);
    }
    float bv = m2b[nt * 16 + mrow];
#pragma unroll
    for (int r = 0; r < 4; ++r) acc[r] += bv;
    acc2[nt] = acc;
  }

  // ---- LN stats: rows kgrp*4+r, reduce over 16 lanes of this quarter ----
  float s1[4] = {0.f, 0.f, 0.f, 0.f}, s2[4] = {0.f, 0.f, 0.f, 0.f};
#pragma unroll
  for (int nt = 0; nt < 8; ++nt)
#pragma unroll
    for (int r = 0; r < 4; ++r) {
      float v = acc2[nt][r];
      s1[r] += v; s2[r] += v * v;
    }
#pragma unroll
  for (int r = 0; r < 4; ++r) {
#pragma unroll
    for (int o = 1; o < 16; o <<= 1) {
      s1[r] += __shfl_xor(s1[r], o);
      s2[r] += __shfl_xor(s2[r], o);
    }
  }
  float mu[4], rstd[4];
#pragma unroll
  for (int r = 0; r < 4; ++r) {
    mu[r] = s1[r] * (1.f / Hdim);
    float var = fmaxf(s2[r] * (1.f / Hdim) - mu[r] * mu[r], 0.f);
    rstd[r] = rsqrtf(var + 1e-5f);
  }

  // ---- epilogue: LN affine, relu, +residual, store x + xh ----
#pragma unroll
  for (int nt = 0; nt < 8; ++nt) {
    int col = nt * 16 + mrow;
    float g = lng[col], bb = lnb[col];
#pragma unroll
    for (int r = 0; r < 4; ++r) {
      int row = row0 + kgrp * 4 + r;
      float y = (acc2[nt][r] - mu[r]) * rstd[r] * g + bb;
      float xr = x[(size_t)row * Hdim + col];
      float o = fmaxf(y, 0.f) + xr;
      x[(size_t)row * Hdim + col] = o;
      xh[(size_t)row * Hdim + col] = (_Float16)o;
    }
  }
}

// ---------------- one GRU step, 16 rows/WG (128 threads) --------------------
// state rows are (b*N+n); x rows are (n*TC+tin)*Bdim+b in the chunk buffer.
// RACE NOTE: GEMM phase reads ALL channels of this block's hg rows; write
// phase overwrites them. __syncthreads() orders read-before-write (the r3/r4
// 0.1-absmax bug). Rows are block-private so a workgroup barrier suffices.
__global__ __launch_bounds__(128, 2) void gru_kernel(
    const float* __restrict__ x, float* __restrict__ hg,
    const float* __restrict__ wih, const float* __restrict__ whh,
    const float* __restrict__ bih, const float* __restrict__ bhh,
    int N, int tin)
{
  const int ROWS = 16;
  int row0 = blockIdx.x * ROWS;
  int j = threadIdx.x;

  int xrow[ROWS];
#pragma unroll
  for (int r = 0; r < ROWS; ++r) {
    int rr = row0 + r;
    int b = rr / N, n = rr - b * N;
    xrow[r] = (n * TC + tin) * Bdim + b;
  }

  float air[ROWS], aiz[ROWS], ain[ROWS], ahr[ROWS], ahz[ROWS], ahn[ROWS];
  float bir = bih[j], biz = bih[Hdim + j], bin_ = bih[2 * Hdim + j];
  float bhr = bhh[j], bhz = bhh[Hdim + j], bhn = bhh[2 * Hdim + j];
#pragma unroll
  for (int r = 0; r < ROWS; ++r) {
    air[r] = bir; aiz[r] = biz; ain[r] = bin_;
    ahr[r] = bhr; ahz[r] = bhz; ahn[r] = bhn;
  }

  const float2* x2 = (const float2*)x;
  const float2* h2p = (const float2*)hg;
  for (int i2 = 0; i2 < Hdim / 2; ++i2) {
    int i = i2 * 2;
    float w0a = wih[(i + 0) * 384 + j], w0b = wih[(i + 0) * 384 + 128 + j], w0c = wih[(i + 0) * 384 + 256 + j];
    float w1a = wih[(i + 1) * 384 + j], w1b = wih[(i + 1) * 384 + 128 + j], w1c = wih[(i + 1) * 384 + 256 + j];
    float v0a = whh[(i + 0) * 384 + j], v0b = whh[(i + 0) * 384 + 128 + j], v0c = whh[(i + 0) * 384 + 256 + j];
    float v1a = whh[(i + 1) * 384 + j], v1b = whh[(i + 1) * 384 + 128 + j], v1c = whh[(i + 1) * 384 + 256 + j];
#pragma unroll
    for (int r = 0; r < ROWS; ++r) {
      float2 xv = x2[(size_t)xrow[r] * 64 + i2];         // uniform -> s_load
      float2 hv = h2p[(size_t)(row0 + r) * 64 + i2];     // uniform -> s_load
      air[r] += xv.x * w0a + xv.y * w1a;
      aiz[r] += xv.x * w0b + xv.y * w1b;
      ain[r] += xv.x * w0c + xv.y * w1c;
      ahr[r] += hv.x * v0a + hv.y * v1a;
      ahz[r] += hv.x * v0b + hv.y * v1b;
      ahn[r] += hv.x * v0c + hv.y * v1c;
    }
  }

  __syncthreads();   // all waves finish reading hg before any wave writes it

#pragma unroll
  for (int r = 0; r < ROWS; ++r) {
    float rr = 1.f / (1.f + expf(-(air[r] + ahr[r])));
    float zz = 1.f / (1.f + expf(-(aiz[r] + ahz[r])));
    float nn = tanhf(ain[r] + rr * ahn[r]);
    float hold = hg[(size_t)(row0 + r) * Hdim + j];
    hg[(size_t)(row0 + r) * Hdim + j] = (1.f - zz) * nn + zz * hold;
  }
}

// ---------------- head: out[row] = dot(h[row], head_w) + head_b -------------
__global__ __launch_bounds__(128) void head_kernel(
    const float* __restrict__ hg, const float* __restrict__ hw,
    const float* __restrict__ hb, float* __restrict__ out)
{
  int row = blockIdx.x;
  int j = threadIdx.x;
  __shared__ float red[2];
  float v = hg[(size_t)row * Hdim + j] * hw[j];
#pragma unroll
  for (int off = 32; off >= 1; off >>= 1) v += __shfl_xor(v, off);
  int wid = j >> 6, lane = j & 63;
  if (lane == 0) red[wid] = v;
  __syncthreads();
  if (j == 0) out[row] = red[0] + red[1] + hb[0];
}

extern "C" void kernel_launch(void* const* d_in, const int* in_sizes, int n_in,
                              void* d_out, int out_size, void* d_ws, size_t ws_size,
                              hipStream_t stream)
{
  const float* xseq  = (const float*)d_in[0];
  const int*   ei    = (const int*)d_in[1];
  const float* attr  = (const float*)d_in[2];
  const float* enc_w = (const float*)d_in[3];
  const float* enc_b = (const float*)d_in[4];
  const float* eW    = (const float*)d_in[5];
  const float* eb    = (const float*)d_in[6];
  const float* m1w   = (const float*)d_in[7];
  const float* m1b   = (const float*)d_in[8];
  const float* m2w   = (const float*)d_in[9];
  const float* m2b   = (const float*)d_in[10];
  const float* lng   = (const float*)d_in[11];
  const float* lnb   = (const float*)d_in[12];
  const float* wih   = (const float*)d_in[13];
  const float* whh   = (const float*)d_in[14];
  const float* bih   = (const float*)d_in[15];
  const float* bhh   = (const float*)d_in[16];
  const float* hw    = (const float*)d_in[17];
  const float* hb    = (const float*)d_in[18];

  int E = in_sizes[1] / 2;
  int N = in_sizes[0] / (Bdim * Tdim * Fdim);
  int rowsState = Bdim * N;                    // 20000
  int rowsC = TC * Bdim * N;                   // 80000
  size_t SC = (size_t)rowsC * Hdim;            // chunk buffer floats
  size_t SS = (size_t)rowsState * Hdim;        // state buffer floats

  float*     x   = (float*)d_ws;
  float*     agg = x + SC;
  float*     hgb = agg + SC;
  _Float16*  xh  = (_Float16*)(hgb + SS);      // fp16 shadow, SC elements
  _Float16*  wpk = xh + SC;                    // packed weights: 4 * 16384 halfs
  int*   cnt  = (int*)(wpk + 4 * 16384);
  int*   off  = cnt + N;
  int*   eids = off + (N + 1);
  int*   src_csr = eids + E;

  hipMemsetAsync(hgb, 0, SS * sizeof(float), stream);
  hipMemsetAsync(cnt, 0, N * sizeof(int), stream);

  int eBlocks    = (E + 255) / 256;
  int encBlocks  = (rowsC * 32 + 255) / 256;   // 10000
  int mlpBlocks  = rowsC / 64;                 // 1250
  int gruBlocks  = rowsState / 16;             // 1250
  int pullBlocks = (N + 3) / 4;                // 2500

  count_kernel<<<eBlocks, 256, 0, stream>>>(ei, cnt, E);
  scan_kernel<<<1, 1024, 0, stream>>>(cnt, off, N);
  fill_kernel<<<eBlocks, 256, 0, stream>>>(ei, off, eids, src_csr, E);
  for (int l = 0; l < 2; ++l) {
    pack_w_kernel<<<8, 256, 0, stream>>>(m1w + (size_t)l * Hdim * Hdim,
                                         wpk + (size_t)(2 * l) * 16384);
    pack_w_kernel<<<8, 256, 0, stream>>>(m2w + (size_t)l * Hdim * Hdim,
                                         wpk + (size_t)(2 * l + 1) * 16384);
  }

  for (int c = 0; c < Tdim / TC; ++c) {
    enc_kernel<<<encBlocks, 256, 0, stream>>>(xseq, enc_w, enc_b, x, xh, N, c * TC);
    for (int l = 0; l < 2; ++l) {
      pull_kernel<<<pullBlocks, 256, 0, stream>>>(
          x, xh, agg, src_csr, off, eids, attr,
          eW + (size_t)l * Ddim * Hdim, eb + (size_t)l * Hdim, N);
      mlp_mfma_kernel<<<mlpBlocks, 256, 0, stream>>>(
          x, xh, agg,
          wpk + (size_t)(2 * l) * 16384, wpk + (size_t)(2 * l + 1) * 16384,
          m1b + (size_t)l * Hdim, m2b + (size_t)l * Hdim,
          lng + (size_t)l * Hdim, lnb + (size_t)l * Hdim);
    }
    for (int tin = 0; tin < TC; ++tin)
      gru_kernel<<<gruBlocks, 128, 0, stream>>>(x, hgb, wih, whh, bih, bhh, N, tin);
  }
  head_kernel<<<rowsState, 128, 0, stream>>>(hgb, hw, hb, (float*)d_out);
}